// Round 11
// baseline (90.931 us; speedup 1.0000x reference)
//
#include <hip/hip_runtime.h>
#include <hip/hip_bf16.h>

#define MTOK 16384
#define DDIM 2048
#define NEXP 8
#define RNK 16
#define NC 128          // E*R down-projection columns
#define NW 160          // padded GEMM1 N: 128 h + 8 logits + 24 zero pad
#define LOGIT0 128
#define KSPLIT 4
#define KLEN (DDIM / KSPLIT)   // 512
#define NT (KLEN / 64)         // 8 K-steps of 64
#define BM1 128                // gemm1 rows per block

typedef __attribute__((ext_vector_type(8))) short bf16x8;
typedef __attribute__((ext_vector_type(4))) short short4v;
typedef __attribute__((ext_vector_type(4))) float f32x4;

typedef __attribute__((address_space(1))) const void gv_t;
typedef __attribute__((address_space(3))) void lv_t;

__device__ __forceinline__ short f2b(float f) {
  unsigned u = __float_as_uint(f);
  u += 0x7fffu + ((u >> 16) & 1u);   // round-to-nearest-even
  return (short)(u >> 16);
}
__device__ __forceinline__ float b2f(short s) {
  return __uint_as_float(((unsigned)(unsigned short)s) << 16);
}

// ---------------- K0: weight prep (fp32 -> bf16) ---------------------------
// WdT tile-contiguous (r10 layout, proven): 32 tiles (per 64-k slice) x 1280
// 16B-units in LDS-image order; unit u of tile t holds logical row n=u>>3,
// k-chunk c=(u&7)^(n&7) (XOR swizzle baked), k = t*64 + c*8 ..+7.
// Logical W[n][k]: n<128 -> down[n>>4][k][n&15]; 128..135 -> rw[n-128][k]; else 0
// UT[d][c]: up[c>>4][c&15][d]  (B-operand N x K for gemm2)
__global__ __launch_bounds__(256) void prep_k(const float* __restrict__ rw,
                                              const float* __restrict__ down,
                                              const float* __restrict__ up,
                                              short* __restrict__ WdT,
                                              short* __restrict__ UT) {
  int i = blockIdx.x * 256 + threadIdx.x;
  const int NWD = NW * DDIM;          // 327680 = 32 tiles * 1280 units * 8
  const int NUT = DDIM * NC;          // 262144
  if (i < NWD) {
    int t = i / (160 * 64);           // k-tile
    int r = i % (160 * 64);
    int u = r >> 3, e = r & 7;        // 16B unit, element within
    int n = u >> 3, s = u & 7;        // logical row, LDS slot
    int c = s ^ (n & 7);              // logical k-chunk (XOR swizzle baked)
    int k = t * 64 + c * 8 + e;
    float v = 0.f;
    if (n < NC)             v = down[((n >> 4) * DDIM + k) * RNK + (n & 15)];
    else if (n < NC + NEXP) v = rw[(n - NC) * DDIM + k];
    WdT[i] = f2b(v);
  } else if (i < NWD + NUT) {
    int u2 = i - NWD;
    int d = u2 >> 7, c2 = u2 & 127;
    UT[u2] = f2b(up[((c2 >> 4) * RNK + (c2 & 15)) * DDIM + d]);
  }
}

// ---------------- K1: GEMM1  Hp[ks][16384][160] (bf16) = X @ W^T -----------
// Guide T3 "minimum 2-phase": ONE __syncthreads per K-step, stage issued
// BEFORE compute, no inline asm, no sched_barrier -- compiler schedules.
// BM=128, KSPLIT=4 (grid 512, 2 blocks/CU, LDS 76 KB). 4 waves: 2x2, each
// 64 rows x 80 cols (acc 4x5).
__global__ __launch_bounds__(256, 2) void gemm1_k(const float* __restrict__ X,
                                                  const short* __restrict__ WdT,
                                                  short* __restrict__ Hp) {
  __shared__ short Al[2][BM1][72];     // 36864 B (+8 pad)
  __shared__ short Bl[2][160 * 64];    // 40960 B, linear for global_load_lds
  const int tid = threadIdx.x;
  const int lane = tid & 63;
  const int w = tid >> 6;
  const int gm0 = blockIdx.x * BM1;
  const int ks = blockIdx.y;
  const int kb = ks * KLEN;
  const int wr = (w & 1) * 64;         // wave row base (4 m-frags)
  const int wc = (w >> 1) * 80;        // wave col base (5 n-frags)
  const int lr = lane & 15;
  const int lk = (lane >> 4) * 8;

  f32x4 acc[4][5];
#pragma unroll
  for (int m = 0; m < 4; ++m)
#pragma unroll
    for (int n = 0; n < 5; ++n) acc[m][n] = (f32x4){0.f, 0.f, 0.f, 0.f};

  float4 aR[8];   // A staging: 128x64 fp32 = 256 thr * 8 * float4

  auto loadA = [&](int k0) {
#pragma unroll
    for (int i2 = 0; i2 < 8; ++i2) {
      int f = tid + 256 * i2;          // 2048 chunks: 128 rows x 16 float4
      int row = f >> 4, c4 = f & 15;
      aR[i2] = *(const float4*)(X + (size_t)(gm0 + row) * DDIM + k0 + c4 * 4);
    }
  };
  auto issueB = [&](int buf, int k0) {
    // tile (k0>>6): 1280 contiguous 16B units; wave w copies 5 x 1KB dense.
    const short* tbase = WdT + (size_t)(k0 >> 6) * (160 * 64);
#pragma unroll
    for (int j = 0; j < 5; ++j) {
      int call = w * 5 + j;
      const short* g = tbase + ((size_t)call * 64 + lane) * 8;
      short* l = &Bl[buf][call * 512];   // wave-uniform base
      __builtin_amdgcn_global_load_lds((gv_t*)g, (lv_t*)l, 16, 0, 0);
    }
  };
  auto writeA = [&](int buf) {
#pragma unroll
    for (int i2 = 0; i2 < 8; ++i2) {
      int f = tid + 256 * i2;
      int row = f >> 4, c4 = f & 15;
      short4v v;
      v.x = f2b(aR[i2].x); v.y = f2b(aR[i2].y);
      v.z = f2b(aR[i2].z); v.w = f2b(aR[i2].w);
      *(short4v*)&Al[buf][row][c4 * 4] = v;
    }
  };
  auto compute = [&](int buf) {
#pragma unroll
    for (int kk2 = 0; kk2 < 2; ++kk2) {
      const int kk = kk2 * 32;
      bf16x8 a[4], b[5];
#pragma unroll
      for (int m = 0; m < 4; ++m)
        a[m] = *(const bf16x8*)&Al[buf][wr + m * 16 + lr][kk + lk];
#pragma unroll
      for (int n = 0; n < 5; ++n) {
        int row = wc + n * 16 + lr;
        int sl = ((kk >> 3) + (lane >> 4)) ^ (row & 7);   // swizzled 16B slot
        b[n] = *(const bf16x8*)&Bl[buf][row * 64 + sl * 8];
      }
#pragma unroll
      for (int m = 0; m < 4; ++m)
#pragma unroll
        for (int n = 0; n < 5; ++n)
          acc[m][n] = __builtin_amdgcn_mfma_f32_16x16x32_bf16(a[m], b[n], acc[m][n], 0, 0, 0);
    }
  };

  // prologue: stage tile 0
  loadA(kb);
  issueB(0, kb);
  writeA(0);
  __syncthreads();

  // main loop: stage(t+1) issued BEFORE compute(t); ONE barrier per step.
#pragma unroll
  for (int t = 0; t < NT; ++t) {
    const int cur = t & 1, nxt = cur ^ 1;
    if (t + 1 < NT) {
      loadA(kb + (t + 1) * 64);        // global->reg, overlaps compute below
      issueB(nxt, kb + (t + 1) * 64);  // global->LDS, overlaps compute below
    }
    compute(cur);
    if (t + 1 < NT) writeA(nxt);       // reg->LDS (other buffer)
    __syncthreads();                   // drains vm+lgkm once per step
  }

  short* Hq = Hp + (size_t)ks * MTOK * NW;
  const int cr = (lane >> 4) * 4;
#pragma unroll
  for (int m = 0; m < 4; ++m)
#pragma unroll
    for (int n = 0; n < 5; ++n)
#pragma unroll
      for (int r = 0; r < 4; ++r) {
        int row = gm0 + wr + m * 16 + cr + r;
        int col = wc + n * 16 + lr;
        Hq[(size_t)row * NW + col] = f2b(acc[m][n][r]);
      }
}

// ---------------- K2: routing — sum 4 split-K slices, top2, scale -> Hw ----
__global__ __launch_bounds__(256) void route_k(const short* __restrict__ Hp,
                                               short* __restrict__ Hw) {
  __shared__ float wv[64][8];
  const int tid = threadIdx.x;
  const int t0 = blockIdx.x * 64;
  if (tid < 64) {
    int t = t0 + tid;
    float lg[8] = {0.f, 0.f, 0.f, 0.f, 0.f, 0.f, 0.f, 0.f};
#pragma unroll
    for (int s = 0; s < KSPLIT; ++s) {
      uint4 l = *(const uint4*)(Hp + (size_t)s * MTOK * NW + (size_t)t * NW + LOGIT0);
      const short* p = (const short*)&l;
#pragma unroll
      for (int e = 0; e < 8; ++e) lg[e] += b2f(p[e]);
    }
    float b0 = -1e30f, b1 = -1e30f;
    int i0 = 0, i1 = 0;
#pragma unroll
    for (int e = 0; e < 8; ++e) {
      float v = lg[e];
      if (v > b0) { b1 = b0; i1 = i0; b0 = v; i0 = e; }   // lax.top_k tie-break
      else if (v > b1) { b1 = v; i1 = e; }
    }
    float ex = __expf(b1 - b0);
    float inv = 1.f / (1.f + ex);
#pragma unroll
    for (int e = 0; e < 8; ++e)
      wv[tid][e] = (e == i0) ? inv : ((e == i1) ? ex * inv : 0.f);
  }
  __syncthreads();
  const int t = tid >> 2, q = tid & 3;     // token, col-quarter (32 cols)
  short* o = Hw + (size_t)(t0 + t) * NC + q * 32;
#pragma unroll
  for (int j = 0; j < 4; ++j) {
    float h[8] = {0.f, 0.f, 0.f, 0.f, 0.f, 0.f, 0.f, 0.f};
#pragma unroll
    for (int s = 0; s < KSPLIT; ++s) {
      uint4 v = *(const uint4*)(Hp + (size_t)s * MTOK * NW + (size_t)(t0 + t) * NW + q * 32 + j * 8);
      const short* p = (const short*)&v;
#pragma unroll
      for (int e2 = 0; e2 < 8; ++e2) h[e2] += b2f(p[e2]);
    }
    short r[8];
    int cbase = q * 32 + j * 8;
#pragma unroll
    for (int e2 = 0; e2 < 8; ++e2)
      r[e2] = f2b(h[e2] * wv[t][(cbase + e2) >> 4]);
    *(uint4*)(o + j * 8) = *(uint4*)r;
  }
}

// ---------------- K3: GEMM2 + residual  Out = X + Hw @ U -------------------
// BM=128, BN=64, K=128 single stage. Epilogue transposes acc through each
// wave's PRIVATE LDS slice (== its own A rows, no barrier) for float4 I/O.
__global__ __launch_bounds__(256) void gemm2_k(const short* __restrict__ Hw,
                                               const short* __restrict__ UT,
                                               const float* __restrict__ X,
                                               float* __restrict__ Out) {
  __shared__ short Al[128][136];   // +8 pad, row stride 272B (34816 B)
  __shared__ short Bl[64][136];
  const int tid = threadIdx.x;
  const int lane = tid & 63;
  const int w = tid >> 6;
  const int gm0 = blockIdx.x * 128;
  const int n0 = blockIdx.y * 64;
  const int lr = lane & 15;
  const int lk = (lane >> 4) * 8;

#pragma unroll
  for (int i = 0; i < 8; ++i) {
    int f = tid + 256 * i;         // 128 rows x 16 chunks(16B)
    int row = f >> 4, c8 = f & 15;
    *(uint4*)&Al[row][c8 * 8] = *(const uint4*)(Hw + (size_t)(gm0 + row) * NC + c8 * 8);
  }
#pragma unroll
  for (int i = 0; i < 4; ++i) {
    int f = tid + 256 * i;         // 64 rows x 16 chunks
    int row = f >> 4, c8 = f & 15;
    *(uint4*)&Bl[row][c8 * 8] = *(const uint4*)(UT + (size_t)(n0 + row) * NC + c8 * 8);
  }
  __syncthreads();

  f32x4 acc[2][4];
#pragma unroll
  for (int m = 0; m < 2; ++m)
#pragma unroll
    for (int n = 0; n < 4; ++n) acc[m][n] = (f32x4){0.f, 0.f, 0.f, 0.f};

#pragma unroll
  for (int ks = 0; ks < 4; ++ks) {
    const int kk = ks * 32;
    bf16x8 a[2], b[4];
#pragma unroll
    for (int m = 0; m < 2; ++m) a[m] = *(const bf16x8*)&Al[w * 32 + m * 16 + lr][kk + lk];
#pragma unroll
    for (int n = 0; n < 4; ++n) b[n] = *(const bf16x8*)&Bl[n * 16 + lr][kk + lk];
#pragma unroll
    for (int m = 0; m < 2; ++m)
#pragma unroll
      for (int n = 0; n < 4; ++n)
        acc[m][n] = __builtin_amdgcn_mfma_f32_16x16x32_bf16(a[m], b[n], acc[m][n], 0, 0, 0);
  }

  // Epilogue: wave-private LDS transpose (bytes [w*8704, (w+1)*8704) ==
  // exactly Al rows [w*32, w*32+32), which only this wave read as A-frags).
  float* eps = (float*)&Al[0][0] + w * 2176;   // 32 rows x 68 floats
  const int cr = (lane >> 4) * 4;
#pragma unroll
  for (int m = 0; m < 2; ++m)
#pragma unroll
    for (int n = 0; n < 4; ++n)
#pragma unroll
      for (int r = 0; r < 4; ++r)
        eps[(m * 16 + cr + r) * 68 + n * 16 + lr] = acc[m][n][r];

#pragma unroll
  for (int j = 0; j < 8; ++j) {
    int c = lane + 64 * j;         // 512 float4-chunks: 32 rows x 16
    int rl = c >> 4, c4 = c & 15;
    float4 v = *(const float4*)&eps[rl * 68 + c4 * 4];
    size_t idx = (size_t)(gm0 + w * 32 + rl) * DDIM + n0 + c4 * 4;
    const float4 xv = *(const float4*)(X + idx);
    v.x += xv.x; v.y += xv.y; v.z += xv.z; v.w += xv.w;
    *(float4*)(Out + idx) = v;
  }
}

// ---------------------------------------------------------------------------
extern "C" void kernel_launch(void* const* d_in, const int* in_sizes, int n_in,
                              void* d_out, int out_size, void* d_ws, size_t ws_size,
                              hipStream_t stream) {
  const float* x    = (const float*)d_in[0];
  const float* rw   = (const float*)d_in[1];
  const float* down = (const float*)d_in[2];
  const float* up   = (const float*)d_in[3];
  float* out = (float*)d_out;

  char* ws = (char*)d_ws;
  short* WdT = (short*)ws;                          // 160*2048*2          =   655360 B
  short* UT  = (short*)(ws + 655360);               // 2048*128*2          =   524288 B
  short* Hp  = (short*)(ws + 1179648);              // 4*16384*160*2       = 20971520 B
  short* Hw  = (short*)(ws + 22151168);             // 16384*128*2         =  4194304 B
                                                    // total 26345472 B

  prep_k<<<2304, 256, 0, stream>>>(rw, down, up, WdT, UT);
  gemm1_k<<<dim3(MTOK / BM1, KSPLIT), 256, 0, stream>>>(x, WdT, Hp);        // 512 blocks
  route_k<<<MTOK / 64, 256, 0, stream>>>(Hp, Hw);                           // 256 blocks
  gemm2_k<<<dim3(MTOK / 128, DDIM / 64), 256, 0, stream>>>(Hw, UT, x, out); // 4096 blocks
}